// Round 4
// baseline (418.660 us; speedup 1.0000x reference)
//
#include <hip/hip_runtime.h>
#include <hip/hip_bf16.h>

// Implicit-GEMM conv: M = 32*54*54 = 93312, N = 256 (co), K = 9*256 = 2304.
// R7 = R4 (best measured: ring-4, stage-ahead-3, vmcnt(6), 1 barrier/tile,
//      setprio) + CONTIGUOUS fragment LDS layout:
//   tile stored as [group(16 rows)][fq(4)][fm(16)] 16B units, so every frag
//   ds_read_b128 is base + lane*16 -> one contiguous 1KB per wave-read
//   (m134's 12-cyc pattern, bank-conflict-free). XOR swizzle deleted.
//   glds dest stays linear (wave-uniform + lane*16); only per-lane GLOBAL
//   source mapping changed (lane -> row w*16+(l&15), chunk l>>4).
// R5/R6 cross-tile frag prefetch abandoned (two-round regression: fences broke
// the compiler's fine-grained lgkmcnt interleave; serial-sum is the schedule).

typedef __bf16 bf16x8 __attribute__((ext_vector_type(8)));
typedef float f32x4 __attribute__((ext_vector_type(4)));

#define GLOBAL_AS __attribute__((address_space(1)))
#define LDS_AS __attribute__((address_space(3)))

static __device__ __forceinline__ void glds16(const void* g, void* l) {
    __builtin_amdgcn_global_load_lds((const GLOBAL_AS unsigned int*)g,
                                     (LDS_AS unsigned int*)l, 16, 0, 0);
}

static __device__ __forceinline__ unsigned short f2bf(float f) {
    unsigned int u = __float_as_uint(f);
    unsigned int r = u + 0x7FFFu + ((u >> 16) & 1u);  // RNE
    return (unsigned short)(r >> 16);
}

// ---- conversion: blocks [0,2048) grid-stride convert x; [2048,2304) convert w ----
__global__ __launch_bounds__(256) void cvt_xw(
    const float* __restrict__ x, unsigned short* __restrict__ xb,
    const float* __restrict__ w, unsigned short* __restrict__ wt) {
    if (blockIdx.x < 2048) {
        const int NV4 = 32 * 56 * 56 * 256 / 4;  // 6,422,528 float4 elements
        const int stride = 2048 * 256;
        const float4* __restrict__ src = (const float4*)x;
        ushort4* __restrict__ dst = (ushort4*)xb;
        for (int j = blockIdx.x * 256 + threadIdx.x; j < NV4; j += stride) {
            float4 a = src[j];
            ushort4 o;
            o.x = f2bf(a.x); o.y = f2bf(a.y); o.z = f2bf(a.z); o.w = f2bf(a.w);
            dst[j] = o;
        }
    } else {
        int co = blockIdx.x - 2048;
        int ci = threadIdx.x;
        const float* src = w + co * 2304 + ci * 9;
        unsigned short* dst = wt + co * 2304 + ci;
#pragma unroll
        for (int khw = 0; khw < 9; ++khw) {
            float v = src[khw];
            v = (fabsf(v) < 0.01f) ? 0.0f : v;
            dst[khw * 256] = f2bf(v);
        }
    }
}

// ---- GEMM: Out[m][co] = sum_k A[m][k]*Wt[co][k] + bias[co] ----
__global__ __launch_bounds__(512, 2) void conv_gemm(
    const unsigned short* __restrict__ Xb,   // bf16 bits [32*56*56*256]
    const unsigned short* __restrict__ Wt,   // bf16 bits [256][2304]
    const float* __restrict__ bias,          // [256]
    float* __restrict__ Out)                 // [93312][256]
{
    // 4-deep ring: per K-tile buffer A 128x32 (8KB) + B 256x32 (16KB) -> 96KB
    // layout (16B units): A: [g(8)][fq(4)][fm(16)]   B: [g(16)][fq(4)][fm(16)]
    __shared__ __align__(16) unsigned short As[4][128 * 32];
    __shared__ __align__(16) unsigned short Bs[4][256 * 32];

    const int tid  = threadIdx.x;            // 0..511
    const int lane = tid & 63;
    const int wave = tid >> 6;               // 0..7

    const int m0 = blockIdx.x * 128;         // 729 blocks, co0 = 0 (BN = full 256)

    // ---- staging source addresses (lane -> (row, chunk) for contiguous LDS) ----
    // A unit tid: g = wave, fm = tid&15, fq = (tid>>4)&3  -> row = wave*16+fm
    const int sfm = tid & 15;
    const int sfq = (tid >> 4) & 3;
    int am = m0 + wave * 16 + sfm;
    int an = am / 2916;
    int arem = am - an * 2916;
    int aoh = arem / 54;
    int aow = arem - aoh * 54;
    const unsigned short* a_base =
        Xb + (((an * 56 + aoh) * 56 + aow) << 8) + sfq * 8;   // kh=kw=0

    // B round 0: group wave (co 0..127); round 1: group 8+wave (co 128..255)
    const int bco0 = wave * 16 + sfm;
    const unsigned short* b_base0 = Wt + bco0 * 2304 + sfq * 8;
    const unsigned short* b_base1 = Wt + (bco0 + 128) * 2304 + sfq * 8;

    // ---- fragment read coordinates ----
    const int fm = lane & 15;
    const int fq = lane >> 4;
    const int wm = (wave >> 2) * 64;         // 2 M-halves
    const int wn = (wave & 3) * 64;          // 4 N-quarters
    const int abase = (wave >> 2) * 2048;    // A group base (shorts): g=wm/16
    const int bbase = (wave & 3) * 2048;     // B group base (shorts): g=wn/16

    f32x4 acc[4][4];
#pragma unroll
    for (int i = 0; i < 4; ++i)
#pragma unroll
        for (int j = 0; j < 4; ++j)
            acc[i][j] = (f32x4){0.f, 0.f, 0.f, 0.f};

    // stage tile tn into ring slot tn&3 (3 glds per thread: 1 A + 2 B)
    auto stage = [&](int tn) {
        const int bn = tn & 3;
        const int khw = tn >> 3;
        const int kh = (khw * 11) >> 5;          // khw/3 for 0..8
        const int kw = khw - kh * 3;
        const int aoff = ((kh * 56 + kw) << 8) + (tn & 7) * 32;
        const int boff = tn * 32;
        glds16(a_base + aoff, &As[bn][wave * 512]);
        glds16(b_base0 + boff, &Bs[bn][wave * 512]);
        glds16(b_base1 + boff, &Bs[bn][4096 + wave * 512]);
    };

    // ---- prologue: stage tiles 0,1,2 (9 loads); vmcnt(6) retires tile 0 ----
#pragma unroll
    for (int tp = 0; tp < 3; ++tp) stage(tp);
    asm volatile("s_waitcnt vmcnt(6)\n\ts_barrier" ::: "memory");

    // ---- main loop: 72 K-tiles; invariant at top of iter t:
    //      tile t LDS-resident, stages {t+1,t+2} outstanding (6 loads) ----
#pragma unroll 1
    for (int t = 0; t < 72; ++t) {
        const int b = t & 3;
        const unsigned short* Ab = As[b];
        const unsigned short* Bb = Bs[b];

        if (t + 3 < 72) stage(t + 3);

        bf16x8 af[4], bfr[4];
#pragma unroll
        for (int mi = 0; mi < 4; ++mi)
            af[mi] = *(const bf16x8*)&Ab[abase + mi * 512 + lane * 8];
#pragma unroll
        for (int ni = 0; ni < 4; ++ni)
            bfr[ni] = *(const bf16x8*)&Bb[bbase + ni * 512 + lane * 8];

        __builtin_amdgcn_s_setprio(1);
#pragma unroll
        for (int mi = 0; mi < 4; ++mi)
#pragma unroll
            for (int ni = 0; ni < 4; ++ni)
                acc[mi][ni] = __builtin_amdgcn_mfma_f32_16x16x32_bf16(
                    af[mi], bfr[ni], acc[mi][ni], 0, 0, 0);
        __builtin_amdgcn_s_setprio(0);

        // counted drain: retire tile t+1's 3 loads; full drain near the tail.
        if (t < 69) asm volatile("s_waitcnt vmcnt(6)\n\ts_barrier" ::: "memory");
        else        asm volatile("s_waitcnt vmcnt(0)\n\ts_barrier" ::: "memory");
    }

    // ---- epilogue: D col = lane&15 (co), row = (lane>>4)*4 + reg (m); fuse bias ----
    float bv[4];
#pragma unroll
    for (int ni = 0; ni < 4; ++ni) bv[ni] = bias[wn + ni * 16 + fm];
#pragma unroll
    for (int mi = 0; mi < 4; ++mi) {
#pragma unroll
        for (int reg = 0; reg < 4; ++reg) {
            int m = m0 + wm + mi * 16 + fq * 4 + reg;
            float* orow = Out + m * 256 + wn + fm;
#pragma unroll
            for (int ni = 0; ni < 4; ++ni)
                orow[ni * 16] = acc[mi][ni][reg] + bv[ni];
        }
    }
}

extern "C" void kernel_launch(void* const* d_in, const int* in_sizes, int n_in,
                              void* d_out, int out_size, void* d_ws, size_t ws_size,
                              hipStream_t stream) {
    const float* x    = (const float*)d_in[0];  // (32,56,56,256) fp32
    const float* w    = (const float*)d_in[1];  // (256,256,3,3) fp32
    const float* bias = (const float*)d_in[2];  // (256,) fp32
    float* out = (float*)d_out;                 // (32,54,54,256) fp32

    const int NX = 32 * 56 * 56 * 256;  // 25,690,112
    unsigned short* xb = (unsigned short*)d_ws;
    unsigned short* wt = xb + NX;

    cvt_xw<<<2304, 256, 0, stream>>>(x, xb, w, wt);
    conv_gemm<<<729, 512, 0, stream>>>(xb, wt, bias, out);
}

// Round 6
// 324.481 us; speedup vs baseline: 1.2902x; 1.2902x over previous
//
#include <hip/hip_runtime.h>
#include <hip/hip_bf16.h>

// Implicit-GEMM conv: M = 32*54*54 = 93312, N = 256 (co), K = 9*256 = 2304.
// R8b: resubmission of R8 (round-5 bench died in container acquisition; kernel
//      audited for deadlock/OOB/spill — clean). Occupancy-overlap + fat waves:
//   - ring-3 LDS (72 KB) -> 2 blocks/CU; cross-block interleave provides the
//     DS/MFMA overlap the per-tile barrier lock-step forbids within a block
//     (m114/m132 mechanism).
//   - 256 threads / 4 waves, wave-tile 128x64: LDS read traffic per tile-block
//     64KB -> 48KB (-25%), same MFMA count.
//   - keeps R4's staging global pattern (quad-contiguous 64B segments + XOR
//     swizzle; R7 proved scrambled fetch order 4x's the TA/L2 request rate)
//     and R4's swizzled frag reads (+4cyc/read conflict tax accepted).
//   - two raw barriers per tile (ring-3: stage(t+3) overwrites slot t%3, must
//     wait for all waves' reads(t)); counted vmcnt(12) steady, 6/0 tail.

typedef __bf16 bf16x8 __attribute__((ext_vector_type(8)));
typedef float f32x4 __attribute__((ext_vector_type(4)));

#define GLOBAL_AS __attribute__((address_space(1)))
#define LDS_AS __attribute__((address_space(3)))

static __device__ __forceinline__ void glds16(const void* g, void* l) {
    __builtin_amdgcn_global_load_lds((const GLOBAL_AS unsigned int*)g,
                                     (LDS_AS unsigned int*)l, 16, 0, 0);
}

static __device__ __forceinline__ unsigned short f2bf(float f) {
    unsigned int u = __float_as_uint(f);
    unsigned int r = u + 0x7FFFu + ((u >> 16) & 1u);  // RNE
    return (unsigned short)(r >> 16);
}

// ---- conversion: blocks [0,2048) grid-stride convert x; [2048,2304) convert w ----
__global__ __launch_bounds__(256) void cvt_xw(
    const float* __restrict__ x, unsigned short* __restrict__ xb,
    const float* __restrict__ w, unsigned short* __restrict__ wt) {
    if (blockIdx.x < 2048) {
        const int NV4 = 32 * 56 * 56 * 256 / 4;  // 6,422,528 float4 elements
        const int stride = 2048 * 256;
        const float4* __restrict__ src = (const float4*)x;
        ushort4* __restrict__ dst = (ushort4*)xb;
        for (int j = blockIdx.x * 256 + threadIdx.x; j < NV4; j += stride) {
            float4 a = src[j];
            ushort4 o;
            o.x = f2bf(a.x); o.y = f2bf(a.y); o.z = f2bf(a.z); o.w = f2bf(a.w);
            dst[j] = o;
        }
    } else {
        int co = blockIdx.x - 2048;
        int ci = threadIdx.x;
        const float* src = w + co * 2304 + ci * 9;
        unsigned short* dst = wt + co * 2304 + ci;
#pragma unroll
        for (int khw = 0; khw < 9; ++khw) {
            float v = src[khw];
            v = (fabsf(v) < 0.01f) ? 0.0f : v;
            dst[khw * 256] = f2bf(v);
        }
    }
}

// LDS swizzle: row's global k-chunk g (8 bf16 = 16B) lives at slot g ^ key(row mod 16).
static __device__ __forceinline__ int swz_key(int row16) {
    return (row16 & 3) ^ ((row16 >> 2) & 3);
}

// ---- GEMM: Out[m][co] = sum_k A[m][k]*Wt[co][k] + bias[co] ----
__global__ __launch_bounds__(256, 2) void conv_gemm(
    const unsigned short* __restrict__ Xb,   // bf16 bits [32*56*56*256]
    const unsigned short* __restrict__ Wt,   // bf16 bits [256][2304]
    const float* __restrict__ bias,          // [256]
    float* __restrict__ Out)                 // [93312][256]
{
    // ring-3: per K-tile buffer A 128x32 (8KB) + B 256x32 (16KB) -> 72KB total
    __shared__ __align__(16) unsigned short As[3][128 * 32];
    __shared__ __align__(16) unsigned short Bs[3][256 * 32];

    const int tid  = threadIdx.x;            // 0..255
    const int lane = tid & 63;
    const int wave = tid >> 6;               // 0..3

    const int m0 = blockIdx.x * 128;         // 729 blocks, co0 = 0 (BN = full 256)

    // ---- staging source addresses (R4 pattern: unit u -> row u>>2, swizzled
    //      chunk (u&3)^key; quad = one row's 4 chunks = contiguous 64B) ----
    const int srow = tid >> 2;               // 0..63
    const int sch  = (tid & 3) ^ swz_key(srow & 15);
    // A rounds r=0,1: row = srow + 64r
    const unsigned short* a_src[2];
#pragma unroll
    for (int r = 0; r < 2; ++r) {
        int am = m0 + srow + 64 * r;
        int an = am / 2916;
        int arem = am - an * 2916;
        int aoh = arem / 54;
        int aow = arem - aoh * 54;
        a_src[r] = Xb + (((an * 56 + aoh) * 56 + aow) << 8) + sch * 8;  // kh=kw=0
    }
    // B rounds r=0..3: co = srow + 64r
    const unsigned short* b_src[4];
#pragma unroll
    for (int r = 0; r < 4; ++r)
        b_src[r] = Wt + (srow + 64 * r) * 2304 + sch * 8;

    // ---- fragment read coordinates (wave-tile 128x64: all rows, cols wave*64) ----
    const int fm = lane & 15;
    const int fq = lane >> 4;
    const int wn = wave * 64;
    const int slot8 = (fq ^ swz_key(fm)) * 8;

    f32x4 acc[8][4];
#pragma unroll
    for (int i = 0; i < 8; ++i)
#pragma unroll
        for (int j = 0; j < 4; ++j)
            acc[i][j] = (f32x4){0.f, 0.f, 0.f, 0.f};

    // stage tile tn into ring slot tn%3 (6 glds per thread: 2 A + 4 B)
    auto stage = [&](int tn) {
        const int bn = tn % 3;
        const int khw = tn >> 3;
        const int kh = (khw * 11) >> 5;          // khw/3 for 0..8
        const int kw = khw - kh * 3;
        const int aoff = ((kh * 56 + kw) << 8) + (tn & 7) * 32;
        const int boff = tn * 32;
#pragma unroll
        for (int r = 0; r < 2; ++r)
            glds16(a_src[r] + aoff, &As[bn][wave * 512 + r * 2048]);
#pragma unroll
        for (int r = 0; r < 4; ++r)
            glds16(b_src[r] + boff, &Bs[bn][wave * 512 + r * 2048]);
    };

    // ---- prologue: stage tiles 0,1,2 (18 loads); vmcnt(12) retires tile 0 ----
#pragma unroll
    for (int tp = 0; tp < 3; ++tp) stage(tp);
    asm volatile("s_waitcnt vmcnt(12)\n\ts_barrier" ::: "memory");

    // ---- main loop: 72 K-tiles.
    //      invariant at top of iter t: tile t LDS-resident, stages {t+1,t+2}
    //      outstanding (12 loads per thread). ----
#pragma unroll 1
    for (int t = 0; t < 72; ++t) {
        const int b = t % 3;
        const unsigned short* Ab = As[b];
        const unsigned short* Bb = Bs[b];

        bf16x8 af[8], bfr[4];
#pragma unroll
        for (int mi = 0; mi < 8; ++mi)
            af[mi] = *(const bf16x8*)&Ab[(mi * 16 + fm) * 32 + slot8];
#pragma unroll
        for (int ni = 0; ni < 4; ++ni)
            bfr[ni] = *(const bf16x8*)&Bb[(wn + ni * 16 + fm) * 32 + slot8];

        __builtin_amdgcn_s_setprio(1);
#pragma unroll
        for (int mi = 0; mi < 8; ++mi)
#pragma unroll
            for (int ni = 0; ni < 4; ++ni)
                acc[mi][ni] = __builtin_amdgcn_mfma_f32_16x16x32_bf16(
                    af[mi], bfr[ni], acc[mi][ni], 0, 0, 0);
        __builtin_amdgcn_s_setprio(0);

        if (t == 71) break;  // last tile: no further sync needed

        // barrier_a: all waves' reads(t) are retired (lgkm-drained before their
        // MFMAs) -> safe for stage(t+3) to overwrite slot t%3. Raw barrier, no
        // waitcnt (compiler must not drain the staging queue here).
        asm volatile("s_barrier" ::: "memory");

        if (t + 3 < 72) stage(t + 3);

        // barrier_b with counted drain: retire tile t+1's 6 loads.
        if (t < 69)
            asm volatile("s_waitcnt vmcnt(12)\n\ts_barrier" ::: "memory");
        else if (t == 69)
            asm volatile("s_waitcnt vmcnt(6)\n\ts_barrier" ::: "memory");
        else
            asm volatile("s_waitcnt vmcnt(0)\n\ts_barrier" ::: "memory");
    }

    // ---- epilogue: D col = lane&15 (co), row = (lane>>4)*4 + reg (m); fuse bias ----
    float bv[4];
#pragma unroll
    for (int ni = 0; ni < 4; ++ni) bv[ni] = bias[wn + ni * 16 + fm];
#pragma unroll
    for (int mi = 0; mi < 8; ++mi) {
#pragma unroll
        for (int reg = 0; reg < 4; ++reg) {
            int m = m0 + mi * 16 + fq * 4 + reg;
            float* orow = Out + m * 256 + wn + fm;
#pragma unroll
            for (int ni = 0; ni < 4; ++ni)
                orow[ni * 16] = acc[mi][ni][reg] + bv[ni];
        }
    }
}

extern "C" void kernel_launch(void* const* d_in, const int* in_sizes, int n_in,
                              void* d_out, int out_size, void* d_ws, size_t ws_size,
                              hipStream_t stream) {
    const float* x    = (const float*)d_in[0];  // (32,56,56,256) fp32
    const float* w    = (const float*)d_in[1];  // (256,256,3,3) fp32
    const float* bias = (const float*)d_in[2];  // (256,) fp32
    float* out = (float*)d_out;                 // (32,54,54,256) fp32

    const int NX = 32 * 56 * 56 * 256;  // 25,690,112
    unsigned short* xb = (unsigned short*)d_ws;
    unsigned short* wt = xb + NX;

    cvt_xw<<<2304, 256, 0, stream>>>(x, xb, w, wt);
    conv_gemm<<<729, 256, 0, stream>>>(xb, wt, bias, out);
}

// Round 7
// 283.691 us; speedup vs baseline: 1.4758x; 1.1438x over previous
//
#include <hip/hip_runtime.h>
#include <hip/hip_bf16.h>

// Implicit-GEMM conv: M = 32*54*54 = 93312, N = 256 (co), K = 9*256 = 2304.
// R9: B-operand direct global->register (weights are 1.18 MB, L2-hot,
//     zero-reuse-amplification in LDS). Removes B from the saturated DS pipe:
//     per block-tile DS drops 1214 -> ~576 cyc vs 620 MFMA cyc.
//   - cvt_xw emits Wt2 in [kchunk(288)][co(256)][8elem] layout so a wave's
//     B-frag load = 4 contiguous 256B segments (coalesced, L1-friendly).
//   - B loaded via inline-asm global_load_dwordx4 (manual VMEM FIFO; ledger:
//     steady outstanding {A(t+1), B(t)x4, A(t+2)} = 6 -> vmcnt(1) before
//     MFMA; t>=70 -> vmcnt(0)). sched_barrier(0) after the wait (rule #18).
//   - A staging/swizzle/epilogue = R4 verbatim; LDS = A-only ring-4 (32 KB).
//   - per-lane B data identical to the old LDS path -> numerics unchanged.

typedef __bf16 bf16x8 __attribute__((ext_vector_type(8)));
typedef float f32x4 __attribute__((ext_vector_type(4)));

#define GLOBAL_AS __attribute__((address_space(1)))
#define LDS_AS __attribute__((address_space(3)))

static __device__ __forceinline__ void glds16(const void* g, void* l) {
    __builtin_amdgcn_global_load_lds((const GLOBAL_AS unsigned int*)g,
                                     (LDS_AS unsigned int*)l, 16, 0, 0);
}

static __device__ __forceinline__ unsigned short f2bf(float f) {
    unsigned int u = __float_as_uint(f);
    unsigned int r = u + 0x7FFFu + ((u >> 16) & 1u);  // RNE
    return (unsigned short)(r >> 16);
}

// ---- conversion: blocks [0,2048) grid-stride convert x; [2048,2304) convert w ----
// w output layout Wt2: element (co, k) -> [(k>>3)*256 + co]*8 + (k&7),
// k = khw*256 + ci  (so kchunk = khw*32 + (ci>>3)).
__global__ __launch_bounds__(256) void cvt_xw(
    const float* __restrict__ x, unsigned short* __restrict__ xb,
    const float* __restrict__ w, unsigned short* __restrict__ wt) {
    if (blockIdx.x < 2048) {
        const int NV4 = 32 * 56 * 56 * 256 / 4;  // 6,422,528 float4 elements
        const int stride = 2048 * 256;
        const float4* __restrict__ src = (const float4*)x;
        ushort4* __restrict__ dst = (ushort4*)xb;
        for (int j = blockIdx.x * 256 + threadIdx.x; j < NV4; j += stride) {
            float4 a = src[j];
            ushort4 o;
            o.x = f2bf(a.x); o.y = f2bf(a.y); o.z = f2bf(a.z); o.w = f2bf(a.w);
            dst[j] = o;
        }
    } else {
        int co = blockIdx.x - 2048;
        int ci = threadIdx.x;
        const float* src = w + co * 2304 + ci * 9;
        unsigned short* dst = wt + ((ci >> 3) * 256 + co) * 8 + (ci & 7);
#pragma unroll
        for (int khw = 0; khw < 9; ++khw) {
            float v = src[khw];
            v = (fabsf(v) < 0.01f) ? 0.0f : v;
            dst[khw * 65536] = f2bf(v);   // khw*32 chunks * 256 co * 8 elem
        }
    }
}

// LDS swizzle: row's global k-chunk g (8 bf16 = 16B) lives at slot g ^ key(row mod 16).
static __device__ __forceinline__ int swz_key(int row16) {
    return (row16 & 3) ^ ((row16 >> 2) & 3);
}

#define LOADB(dst, off)                                                  \
    asm volatile("global_load_dwordx4 %0, %1, %2"                        \
                 : "=v"(dst) : "v"(off), "s"(Wt) : "memory")

// ---- GEMM: Out[m][co] = sum_k A[m][k]*Wt2[co][k] + bias[co] ----
__global__ __launch_bounds__(512, 2) void conv_gemm(
    const unsigned short* __restrict__ Xb,   // bf16 bits [32*56*56*256]
    const unsigned short* __restrict__ Wt,   // bf16 bits, [288 kq][256 co][8]
    const float* __restrict__ bias,          // [256]
    float* __restrict__ Out)                 // [93312][256]
{
    // A-only ring-4: 128x32 bf16 per tile = 8 KB -> 32 KB total
    __shared__ __align__(16) unsigned short As[4][128 * 32];

    const int tid  = threadIdx.x;            // 0..511
    const int lane = tid & 63;
    const int wave = tid >> 6;               // 0..7

    const int m0 = blockIdx.x * 128;         // 729 blocks, BN = full 256

    // ---- A staging source (R4 verbatim: unit tid -> row tid>>2, swizzled chunk) ----
    const int arow = tid >> 2;
    const int ach  = (tid & 3) ^ swz_key(arow & 15);
    int am = m0 + arow;
    int an = am / 2916;
    int arem = am - an * 2916;
    int aoh = arem / 54;
    int aow = arem - aoh * 54;
    const unsigned short* a_base =
        Xb + (((an * 56 + aoh) * 56 + aow) << 8) + ach * 8;   // kh=kw=0

    // ---- fragment read coordinates ----
    const int fm = lane & 15;
    const int fq = lane >> 4;
    const int wm = (wave >> 2) * 64;
    const int wn = (wave & 3) * 64;
    const int slot8 = (fq ^ swz_key(fm)) * 8;

    // B voffset bases (bytes): chunk kq = t*4 + fq, co = wn + ni*16 + fm
    const unsigned int cbb = fq * 4096u + (wn + fm) * 16u;
    const unsigned int cb0 = cbb, cb1 = cbb + 256u, cb2 = cbb + 512u, cb3 = cbb + 768u;

    f32x4 acc[4][4];
#pragma unroll
    for (int i = 0; i < 4; ++i)
#pragma unroll
        for (int j = 0; j < 4; ++j)
            acc[i][j] = (f32x4){0.f, 0.f, 0.f, 0.f};

    // stage A tile tn into ring slot tn&3 (1 glds per thread)
    auto stage = [&](int tn) {
        const int khw = tn >> 3;
        const int kh = (khw * 11) >> 5;          // khw/3 for 0..8
        const int kw = khw - kh * 3;
        const int aoff = ((kh * 56 + kw) << 8) + (tn & 7) * 32;
        glds16(a_base + aoff, &As[tn & 3][wave * 512]);
    };

    // ---- prologue: B(0) then A tiles 0,1,2. FIFO [B0x4, A0, A1, A2];
    //      vmcnt(2) retires B0 + A0, leaves {A1, A2}. ----
    bf16x8 vb0, vb1, vb2, vb3;
    LOADB(vb0, cb0); LOADB(vb1, cb1); LOADB(vb2, cb2); LOADB(vb3, cb3);
    stage(0); stage(1); stage(2);
    asm volatile("s_waitcnt vmcnt(2)\n\ts_barrier" ::: "memory");

    // ---- main loop: 72 K-tiles. Body: ds_read(t) -> vmcnt -> MFMA(t) ->
    //      issue B(t+1) -> stage A(t+3) -> barrier. Steady FIFO at body
    //      entry: [A(t+1), B(t)x4, A(t+2)]; vmcnt(1) retires A(t+1)+B(t). ----
#pragma unroll 1
    for (int t = 0; t < 72; ++t) {
        const unsigned short* Ab = As[t & 3];
        bf16x8 af[4];
#pragma unroll
        for (int mi = 0; mi < 4; ++mi)
            af[mi] = *(const bf16x8*)&Ab[(wm + mi * 16 + fm) * 32 + slot8];

        if (t <= 69) asm volatile("s_waitcnt vmcnt(1)" ::: "memory");
        else         asm volatile("s_waitcnt vmcnt(0)" ::: "memory");
        __builtin_amdgcn_sched_barrier(0);   // rule #18: MFMA must not hoist

        __builtin_amdgcn_s_setprio(1);
#pragma unroll
        for (int mi = 0; mi < 4; ++mi) {
            acc[mi][0] = __builtin_amdgcn_mfma_f32_16x16x32_bf16(af[mi], vb0, acc[mi][0], 0, 0, 0);
            acc[mi][1] = __builtin_amdgcn_mfma_f32_16x16x32_bf16(af[mi], vb1, acc[mi][1], 0, 0, 0);
            acc[mi][2] = __builtin_amdgcn_mfma_f32_16x16x32_bf16(af[mi], vb2, acc[mi][2], 0, 0, 0);
            acc[mi][3] = __builtin_amdgcn_mfma_f32_16x16x32_bf16(af[mi], vb3, acc[mi][3], 0, 0, 0);
        }
        __builtin_amdgcn_s_setprio(0);

        if (t < 71) {  // B(t+1): kq advances by 4 chunks = 16384 B
            const unsigned int off = (unsigned int)(t + 1) * 16384u;
            LOADB(vb0, cb0 + off); LOADB(vb1, cb1 + off);
            LOADB(vb2, cb2 + off); LOADB(vb3, cb3 + off);
        }
        if (t < 69) stage(t + 3);

        // all waves' ds_read(t) results were consumed by MFMA(t) (lgkm-drained)
        // before arriving here -> stage(t+3) overwrite of slot (t-1)&3 is safe.
        asm volatile("s_barrier" ::: "memory");
    }

    // ---- epilogue: D col = lane&15 (co), row = (lane>>4)*4 + reg (m); fuse bias ----
    float bv[4];
#pragma unroll
    for (int ni = 0; ni < 4; ++ni) bv[ni] = bias[wn + ni * 16 + fm];
#pragma unroll
    for (int mi = 0; mi < 4; ++mi) {
#pragma unroll
        for (int reg = 0; reg < 4; ++reg) {
            int m = m0 + wm + mi * 16 + fq * 4 + reg;
            float* orow = Out + m * 256 + wn + fm;
#pragma unroll
            for (int ni = 0; ni < 4; ++ni)
                orow[ni * 16] = acc[mi][ni][reg] + bv[ni];
        }
    }
}

extern "C" void kernel_launch(void* const* d_in, const int* in_sizes, int n_in,
                              void* d_out, int out_size, void* d_ws, size_t ws_size,
                              hipStream_t stream) {
    const float* x    = (const float*)d_in[0];  // (32,56,56,256) fp32
    const float* w    = (const float*)d_in[1];  // (256,256,3,3) fp32
    const float* bias = (const float*)d_in[2];  // (256,) fp32
    float* out = (float*)d_out;                 // (32,54,54,256) fp32

    const int NX = 32 * 56 * 56 * 256;  // 25,690,112
    unsigned short* xb = (unsigned short*)d_ws;
    unsigned short* wt = xb + NX;

    cvt_xw<<<2304, 256, 0, stream>>>(x, xb, w, wt);
    conv_gemm<<<729, 512, 0, stream>>>(xb, wt, bias, out);
}